// Round 2
// baseline (375.000 us; speedup 1.0000x reference)
//
#include <hip/hip_runtime.h>
#include <math.h>

// CellSegmentationLoss: fused focal + dice + boundary-BCE + IoU-aux loss.
// Inputs: d_in[0]=pred_masks (16*1*1024*1024 f32), d_in[1]=gt_masks (same),
//         d_in[2]=pred_iou (16 f32). Output: 1 f32 scalar.
//
// R5: steady-state software pipeline. R3 (one-shot burst) and R4 (tiny
// blocks) both landed ~46-56us with VALUBusy ~30%: the memory system never
// saw a SUSTAINED outstanding-request population (R3 drained between its two
// block generations; R4 paid ~1000cyc/block fixed cost). Fix:
//   - 2048 blocks (exactly 8/CU, ONE generation), 8192 px/block
//   - per wave: 8 chunks x 1024 px, depth-2 prefetch with named rotating
//     buffers (fully unrolled -> static regs, no scratch) => >=4 dwordx4
//     permanently in flight per wave, ~128 KB/CU sustained
//   - loss_final folded in via last-block ticket (one fewer launch)

#define HW_PIX (1024 * 1024)
#define BATCH 16
constexpr int THREADS = 256;
constexpr int BLOCKS = 2048;                            // 8 / CU
constexpr int BLOCKS_PER_IMG = BLOCKS / BATCH;          // 128
constexpr int PIX_PER_BLOCK = HW_PIX / BLOCKS_PER_IMG;  // 8192
constexpr int CHUNK_F4 = THREADS;                       // 1 float4/thread/array
constexpr int CHUNKS = PIX_PER_BLOCK / (CHUNK_F4 * 4);  // 8

struct Accum {
  float fsum, csum, isum, psum;
  unsigned tcnt, bicnt, bpcnt;
};

__device__ __forceinline__ void process4(const float4 xv, const float4 tv,
                                         Accum& a) {
  const float* xs = reinterpret_cast<const float*>(&xv);
  const float* ts = reinterpret_cast<const float*>(&tv);
#pragma unroll
  for (int j = 0; j < 4; ++j) {
    const float xx = xs[j];
    const float tt = ts[j];
    const float e = __expf(-fabsf(xx));                // exp(-|x|) in (0,1]
    const float s = 1.0f + e;
    const float r = __builtin_amdgcn_rcpf(s);
    const float p = (xx >= 0.0f) ? r : e * r;          // sigmoid(x)
    const float ce = fmaxf(xx, 0.0f) - xx * tt + __logf(s);
    const float om = fmaf(tt, 1.0f - 2.0f * p, p);     // 1 - p_t
    const float at = 0.75f - 0.5f * tt;                // alpha_t
    a.fsum += at * ce * om * om;
    a.csum += ce;
    a.isum = fmaf(p, tt, a.isum);
    a.psum += p;
    const unsigned long long mt = __ballot(tt != 0.0f);
    const unsigned long long mb = __ballot(xx > 0.0f); // p>0.5 <=> x>0
    a.tcnt  += (unsigned)__popcll(mt);
    a.bpcnt += (unsigned)__popcll(mb);
    a.bicnt += (unsigned)__popcll(mt & mb);
  }
}

__global__ __launch_bounds__(THREADS, 8) void
loss_fused(const float* __restrict__ x, const float* __restrict__ t,
           const float* __restrict__ pred_iou, float* __restrict__ acc,
           unsigned* __restrict__ ticket, float* __restrict__ out) {
  const int b = blockIdx.x / BLOCKS_PER_IMG;
  const long base = (long)blockIdx.x * PIX_PER_BLOCK;
  const float4* __restrict__ x4 = (const float4*)(x + base);
  const float4* __restrict__ t4 = (const float4*)(t + base);
  const int tid = threadIdx.x;

  Accum a = {0.f, 0.f, 0.f, 0.f, 0u, 0u, 0u};

  // Depth-2 software pipeline over 8 chunks; rotation is static (full unroll)
  float4 xa = x4[tid + 0 * CHUNK_F4], ta = t4[tid + 0 * CHUNK_F4];
  float4 xb = x4[tid + 1 * CHUNK_F4], tb = t4[tid + 1 * CHUNK_F4];
#pragma unroll
  for (int c = 0; c < CHUNKS; ++c) {
    float4 xn = xa, tn = ta;                 // dead init (avoids undef reads)
    if (c + 2 < CHUNKS) {
      xn = x4[tid + (c + 2) * CHUNK_F4];     // issue before consuming chunk c
      tn = t4[tid + (c + 2) * CHUNK_F4];
    }
    process4(xa, ta, a);
    xa = xb; ta = tb;                        // register renames
    xb = xn; tb = tn;
  }

  // Block reduction
  __shared__ float red[THREADS / 64][7];
  const int lane = threadIdx.x & 63;
  const int wave = threadIdx.x >> 6;
  float vals[4] = {a.fsum, a.csum, a.isum, a.psum};
#pragma unroll
  for (int k = 0; k < 4; ++k) {
    float v = vals[k];
#pragma unroll
    for (int off = 32; off > 0; off >>= 1) v += __shfl_down(v, off);
    if (lane == 0) red[wave][k] = v;
  }
  if (lane == 0) {                           // counts are already wave totals
    red[wave][4] = (float)a.tcnt;
    red[wave][5] = (float)a.bicnt;
    red[wave][6] = (float)a.bpcnt;
  }
  __syncthreads();
  if (threadIdx.x < 7) {
    const float s = red[0][threadIdx.x] + red[1][threadIdx.x] +
                    red[2][threadIdx.x] + red[3][threadIdx.x];
    atomicAdd(&acc[b * 8 + threadIdx.x], s); // stride 8: one line/image
  }

  // Last-block finalization (saves the second kernel launch)
  __shared__ unsigned is_last;
  __threadfence();                           // publish this block's adds
  __syncthreads();                           // all fences done before ticket
  if (threadIdx.x == 0)
    is_last = (atomicAdd(ticket, 1u) == (unsigned)(BLOCKS - 1));
  __syncthreads();
  if (is_last && threadIdx.x < 64) {
    __threadfence();                         // acquire: see all blocks' adds
    constexpr float SMOOTH = 1e-6f;
    float F = 0.f, C = 0.f, D = 0.f, Q = 0.f;
    if (lane < BATCH) {
      const float* ap = acc + lane * 8;
      F = ap[0];
      C = ap[1];
      const float I = ap[2], P = ap[3], T = ap[4], BI = ap[5], BP = ap[6];
      D = (2.0f * I + SMOOTH) / (P + T + SMOOTH);          // dice term
      const float iou = (BI + SMOOTH) / (BP + T - BI + SMOOTH);
      const float d = pred_iou[lane] - iou;
      Q = d * d;
    }
#pragma unroll
    for (int off = 32; off > 0; off >>= 1) {
      F += __shfl_down(F, off);
      C += __shfl_down(C, off);
      D += __shfl_down(D, off);
      Q += __shfl_down(Q, off);
    }
    if (lane == 0) {
      const float invN = 1.0f / (float)((long)BATCH * HW_PIX);
      const float focal = F * invN;
      const float dice = 1.0f - D * (1.0f / (float)BATCH);
      const float half_boundary = C * invN;  // 0.5 * (2.0 * mean(ce))
      const float iou_loss = Q * (1.0f / (float)BATCH);
      out[0] = focal + dice + half_boundary + 0.1f * iou_loss;
    }
  }
}

extern "C" void kernel_launch(void* const* d_in, const int* in_sizes, int n_in,
                              void* d_out, int out_size, void* d_ws,
                              size_t ws_size, hipStream_t stream) {
  const float* x = (const float*)d_in[0];
  const float* t = (const float*)d_in[1];
  const float* piou = (const float*)d_in[2];
  float* acc = (float*)d_ws;                               // 128 floats
  unsigned* ticket = (unsigned*)((char*)d_ws + 512);       // 1 uint

  hipMemsetAsync(d_ws, 0, 640, stream);
  loss_fused<<<BLOCKS, THREADS, 0, stream>>>(x, t, piou, acc, ticket,
                                             (float*)d_out);
}

// Round 3
// 218.514 us; speedup vs baseline: 1.7161x; 1.7161x over previous
//
#include <hip/hip_runtime.h>
#include <math.h>

// CellSegmentationLoss: fused focal + dice + boundary-BCE + IoU-aux loss.
// Inputs: d_in[0]=pred_masks (16*1*1024*1024 f32), d_in[1]=gt_masks (same),
//         d_in[2]=pred_iou (16 f32). Output: 1 f32 scalar.
//
// R6: R3 geometry + full single-generation residency + compiler-scheduled
// load window. History:
//   R3 (46us): bounds(256,4) -> 2 generations, occupancy 30%, one-shot burst.
//   R4 (56us): 8192 tiny blocks -> residency ok but ~1000cyc/block overhead
//              + 4x atomic contention.
//   R5 (288us): explicit depth-2 prefetch buffers -> SPILLED to scratch
//              (WRITE_SIZE 194MB). Never hand-roll prefetch regs here.
// Fix: 2048 blocks (8/CU, ONE generation) via bounds(256,8); plain fully
// unrolled loop with loads adjacent to use -- the scheduler forms its own
// outstanding-load window within the 64-VGPR budget (R3/R4 proved it does).
// Accumulator stride 16: one private 64B line per image for the atomics.

#define HW_PIX (1024 * 1024)
#define BATCH 16
constexpr int THREADS = 256;
constexpr int BLOCKS = 2048;                            // 8 / CU, 1 generation
constexpr int BLOCKS_PER_IMG = BLOCKS / BATCH;          // 128
constexpr int PIX_PER_BLOCK = HW_PIX / BLOCKS_PER_IMG;  // 8192
constexpr int F4_PER_THREAD = PIX_PER_BLOCK / (THREADS * 4);  // 8

struct Accum {
  float fsum, csum, isum, psum;
  unsigned tcnt, bicnt, bpcnt;
};

__device__ __forceinline__ void process4(const float4 xv, const float4 tv,
                                         Accum& a) {
  const float* xs = reinterpret_cast<const float*>(&xv);
  const float* ts = reinterpret_cast<const float*>(&tv);
#pragma unroll
  for (int j = 0; j < 4; ++j) {
    const float xx = xs[j];
    const float tt = ts[j];
    const float e = __expf(-fabsf(xx));                // exp(-|x|) in (0,1]
    const float s = 1.0f + e;
    const float r = __builtin_amdgcn_rcpf(s);
    const float p = (xx >= 0.0f) ? r : e * r;          // sigmoid(x)
    const float ce = fmaxf(xx, 0.0f) - xx * tt + __logf(s);
    const float om = fmaf(tt, 1.0f - 2.0f * p, p);     // 1 - p_t
    const float at = 0.75f - 0.5f * tt;                // alpha_t
    a.fsum += at * ce * om * om;
    a.csum += ce;
    a.isum = fmaf(p, tt, a.isum);
    a.psum += p;
    const unsigned long long mt = __ballot(tt != 0.0f);
    const unsigned long long mb = __ballot(xx > 0.0f); // p>0.5 <=> x>0
    a.tcnt  += (unsigned)__popcll(mt);
    a.bpcnt += (unsigned)__popcll(mb);
    a.bicnt += (unsigned)__popcll(mt & mb);
  }
}

__global__ __launch_bounds__(THREADS, 8) void
loss_partial(const float* __restrict__ x, const float* __restrict__ t,
             float* __restrict__ acc) {
  const int b = blockIdx.x / BLOCKS_PER_IMG;
  const long base = (long)blockIdx.x * PIX_PER_BLOCK;
  const float4* __restrict__ x4 = (const float4*)(x + base);
  const float4* __restrict__ t4 = (const float4*)(t + base);
  const int tid = threadIdx.x;

  Accum a = {0.f, 0.f, 0.f, 0.f, 0u, 0u, 0u};

  // Plain unrolled stream: loads written adjacent to use; the scheduler
  // hoists them into an outstanding window sized to the 64-VGPR budget.
  // (Do NOT add explicit prefetch buffers or sched_barrier -- see R5.)
#pragma unroll
  for (int i = 0; i < F4_PER_THREAD; i += 2) {
    const float4 x0 = x4[tid + (i + 0) * THREADS];
    const float4 t0 = t4[tid + (i + 0) * THREADS];
    const float4 x1 = x4[tid + (i + 1) * THREADS];
    const float4 t1 = t4[tid + (i + 1) * THREADS];
    process4(x0, t0, a);
    process4(x1, t1, a);
  }

  __shared__ float red[THREADS / 64][7];
  const int lane = threadIdx.x & 63;
  const int wave = threadIdx.x >> 6;
  float vals[4] = {a.fsum, a.csum, a.isum, a.psum};
#pragma unroll
  for (int k = 0; k < 4; ++k) {
    float v = vals[k];
#pragma unroll
    for (int off = 32; off > 0; off >>= 1) v += __shfl_down(v, off);
    if (lane == 0) red[wave][k] = v;
  }
  if (lane == 0) {                 // counts are already wave totals
    red[wave][4] = (float)a.tcnt;
    red[wave][5] = (float)a.bicnt;
    red[wave][6] = (float)a.bpcnt;
  }
  __syncthreads();
  if (threadIdx.x < 7) {
    const float s = red[0][threadIdx.x] + red[1][threadIdx.x] +
                    red[2][threadIdx.x] + red[3][threadIdx.x];
    atomicAdd(&acc[b * 16 + threadIdx.x], s);  // stride 16: own line/image
  }
}

__global__ void loss_final(const float* __restrict__ acc,
                           const float* __restrict__ pred_iou,
                           float* __restrict__ out) {
  constexpr float SMOOTH = 1e-6f;
  const int lane = threadIdx.x;  // one wave (64), lanes 0..15 active
  float F = 0.f, C = 0.f, D = 0.f, Q = 0.f;
  if (lane < BATCH) {
    const float* a = acc + lane * 16;
    F = a[0];
    C = a[1];
    const float I = a[2], P = a[3], T = a[4], BI = a[5], BP = a[6];
    D = (2.0f * I + SMOOTH) / (P + T + SMOOTH);            // dice term
    const float iou = (BI + SMOOTH) / (BP + T - BI + SMOOTH);
    const float d = pred_iou[lane] - iou;
    Q = d * d;
  }
#pragma unroll
  for (int off = 32; off > 0; off >>= 1) {
    F += __shfl_down(F, off);
    C += __shfl_down(C, off);
    D += __shfl_down(D, off);
    Q += __shfl_down(Q, off);
  }
  if (lane == 0) {
    const float invN = 1.0f / (float)((long)BATCH * HW_PIX);
    const float focal = F * invN;
    const float dice = 1.0f - D * (1.0f / (float)BATCH);
    const float half_boundary = C * invN;  // 0.5 * (2.0 * mean(ce))
    const float iou_loss = Q * (1.0f / (float)BATCH);
    out[0] = focal + dice + half_boundary + 0.1f * iou_loss;
  }
}

extern "C" void kernel_launch(void* const* d_in, const int* in_sizes, int n_in,
                              void* d_out, int out_size, void* d_ws,
                              size_t ws_size, hipStream_t stream) {
  const float* x = (const float*)d_in[0];
  const float* t = (const float*)d_in[1];
  const float* piou = (const float*)d_in[2];
  float* acc = (float*)d_ws;  // BATCH*16 floats

  hipMemsetAsync(acc, 0, BATCH * 16 * sizeof(float), stream);
  loss_partial<<<BLOCKS, THREADS, 0, stream>>>(x, t, acc);
  loss_final<<<1, 64, 0, stream>>>(acc, piou, (float*)d_out);
}